// Round 2
// baseline (115.278 us; speedup 1.0000x reference)
//
#include <hip/hip_runtime.h>
#include <hip/hip_bf16.h>

// ---------------------------------------------------------------------------
// Conv2DKAN: out[b,ho,wo,f] = sum_{di,dj,c,k} feat(x[b,ho+di,wo+dj,c])_k * W[(di,dj,k,c), f]
// feat_k = cubic B-spline basis (k<8) or silu (k==8); W = sk*sf (k<8) or sf.
// One implicit GEMM: M=28800 pixels, N=128 filters, K=81 chunks * 32 channels.
// ---------------------------------------------------------------------------

#define C_IN   32
#define F_OUT  128
#define BATCH  32
#define HIN    32
#define WIN    32
#define HO_    30
#define WO_    30
#define NPIX   (BATCH*HO_*WO_)        // 28800
#define NELEM  (BATCH*HIN*WIN*C_IN)   // 1048576
#define NBASIS 9                      // 8 spline + 1 silu
#define KCHUNKS 81                    // 9 window positions * 9 basis slots
#define FEAT_BYTES  ((size_t)NELEM*NBASIS*2)       // 18,874,368
#define WPACK_BYTES ((size_t)KCHUNKS*F_OUT*32*2)   // 663,552

typedef __attribute__((ext_vector_type(8))) short short8;   // 8 bf16 = 4 VGPR
typedef __attribute__((ext_vector_type(4))) float f32x4;

// async global->LDS, 16B per lane. LDS dest must be linear-in-lane (HW uses
// wave-uniform base + lane*16); our dest = base + tid*16 satisfies this.
#define GLOAD_LDS16(g, l) \
  __builtin_amdgcn_global_load_lds((const __attribute__((address_space(1))) void*)(g), \
                                   (__attribute__((address_space(3))) void*)(l), 16, 0, 0)

// ---------------------------------------------------------------------------
// Kernel A: featurize. feat[bhw][k][c] bf16, 64B per (bhw,k) row.
// Knots g[j] = -2.2 + 0.4j, j=0..11 (GRID_MIN-3h .. GRID_MAX+3h, h=0.4).
// ---------------------------------------------------------------------------
__global__ __launch_bounds__(256) void kan_featurize(
    const float* __restrict__ x, __hip_bfloat16* __restrict__ feat) {
  int idx = blockIdx.x * 256 + threadIdx.x;   // exact grid, no tail
  float v = x[idx];

  float b0[11], b1[10], b2[9], b3[8];
#pragma unroll
  for (int j = 0; j < 11; ++j) {
    float gj  = -2.2f + 0.4f * (float)j;
    float gj1 = -2.2f + 0.4f * (float)(j + 1);
    b0[j] = (v >= gj && v < gj1) ? 1.0f : 0.0f;
  }
#pragma unroll
  for (int j = 0; j < 10; ++j) {  // order 1: denom 0.4
    float gj = -2.2f + 0.4f * (float)j;
    b1[j] = (v - gj) * 2.5f * b0[j] + ((gj + 0.8f) - v) * 2.5f * b0[j + 1];
  }
#pragma unroll
  for (int j = 0; j < 9; ++j) {   // order 2: denom 0.8
    float gj = -2.2f + 0.4f * (float)j;
    b2[j] = (v - gj) * 1.25f * b1[j] + ((gj + 1.2f) - v) * 1.25f * b1[j + 1];
  }
#pragma unroll
  for (int j = 0; j < 8; ++j) {   // order 3: denom 1.2
    float gj = -2.2f + 0.4f * (float)j;
    b3[j] = (v - gj) * (1.0f/1.2f) * b2[j] + ((gj + 1.6f) - v) * (1.0f/1.2f) * b2[j + 1];
  }
  float sil = v / (1.0f + __expf(-v));

  int bhw = idx >> 5, c = idx & 31;
  __hip_bfloat16* o = feat + (size_t)bhw * (NBASIS * 32) + c;
#pragma unroll
  for (int k = 0; k < 8; ++k) o[k * 32] = __float2bfloat16(b3[k]);
  o[8 * 32] = __float2bfloat16(sil);
}

// ---------------------------------------------------------------------------
// Kernel C: pack W -> [kc][col][4 x 16B parts, XOR-swizzled][8 bf16].
// kc = dd*9 + k, dd = di*3+dj; i = dd*32 + csub.
// Swizzle: part p of col r stored at slot p ^ ((r>>1)&3)  (self-inverse).
// ---------------------------------------------------------------------------
__global__ __launch_bounds__(256) void kan_pack_w(
    const float* __restrict__ sk, const float* __restrict__ sf,
    __hip_bfloat16* __restrict__ wp) {
  int tid = blockIdx.x * 256 + threadIdx.x;   // 331776 total, exact
  int csub = tid & 31;
  int col  = (tid >> 5) & 127;
  int kc   = tid >> 12;
  int dd = kc / 9, k = kc - dd * 9;
  int i = dd * 32 + csub;
  float w = sf[i * 128 + col];
  if (k < 8) w *= sk[(i * 8 + k) * 128 + col];
  int part = csub >> 3, within = csub & 7;
  int slot = part ^ ((col >> 1) & 3);
  wp[(size_t)kc * 4096 + col * 32 + slot * 8 + within] = __float2bfloat16(w);
}

// ---------------------------------------------------------------------------
// Kernel B: implicit GEMM. 450 blocks x 256 thr (4 waves, 2x2 of 32x64).
// LDS: A tiles 2x4KB [row 64][64B swz], B tiles 2x8KB [col 128][64B swz].
// ---------------------------------------------------------------------------
__global__ __launch_bounds__(256) void kan_gemm(
    const __hip_bfloat16* __restrict__ featb, const __hip_bfloat16* __restrict__ wpb,
    const float* __restrict__ kbias, const float* __restrict__ cbias,
    float* __restrict__ out) {
  __shared__ char lds[24576];   // A: [0,8K) two bufs; B: [8K,24K) two bufs
  const char* feat = (const char*)featb;
  const char* wp   = (const char*)wpb;

  int tid  = threadIdx.x;
  int lane = tid & 63, wid = tid >> 6;
  int wm = wid >> 1, wn = wid & 1;
  int q = lane >> 4, fr = lane & 15;
  int mb = blockIdx.x * 64;

  // --- A staging source: thread t -> (row=t>>2, slot=t&3); fetch part p s.t.
  //     stored slot holds part p = slot ^ ((row>>1)&3).
  int arow = tid >> 2, aslot = tid & 3;
  int apix = mb + arow;
  int wo = apix % 30, t30 = apix / 30;
  int ho = t30 % 30,  bb  = t30 / 30;
  const char* asrc = feat + (size_t)((bb * 32 + ho) * 32 + wo) * 576
                          + (size_t)((aslot ^ ((arow >> 1) & 3)) * 16);

  // --- fragment LDS byte offsets (swizzled reads)
  int ar0 = 32 * wm + fr, ar1 = ar0 + 16;
  int aoff0 = ar0 * 64 + ((q ^ ((ar0 >> 1) & 3)) * 16);
  int aoff1 = ar1 * 64 + ((q ^ ((ar1 >> 1) & 3)) * 16);
  int boff[4];
#pragma unroll
  for (int n = 0; n < 4; ++n) {
    int col = 64 * wn + 16 * n + fr;
    boff[n] = col * 64 + ((q ^ ((col >> 1) & 3)) * 16);
  }

  f32x4 acc[2][4];
#pragma unroll
  for (int m = 0; m < 2; ++m)
#pragma unroll
    for (int n = 0; n < 4; ++n) acc[m][n] = (f32x4)(0.0f);

  auto stage = [&](int buf, int kc) {
    int dd = kc / 9, k = kc - dd * 9;          // uniform scalar math
    int di = dd / 3, dj = dd - di * 3;
    int au = (di * 32 + dj) * 576 + k * 64;    // window shift + basis slot
    GLOAD_LDS16(asrc + au, lds + buf * 4096 + tid * 16);
    const char* wsrc = wp + (size_t)kc * 8192 + tid * 16;
    GLOAD_LDS16(wsrc,        lds + 8192 + buf * 8192 + tid * 16);
    GLOAD_LDS16(wsrc + 4096, lds + 8192 + buf * 8192 + 4096 + tid * 16);
  };

  stage(0, 0);
  asm volatile("s_waitcnt vmcnt(0)" ::: "memory");
  __syncthreads();

  for (int kc = 0; kc < KCHUNKS; ++kc) {
    int cur = kc & 1;
    if (kc + 1 < KCHUNKS) stage(cur ^ 1, kc + 1);
    const char* A = lds + cur * 4096;
    const char* B = lds + 8192 + cur * 8192;
    short8 a0 = *(const short8*)(A + aoff0);
    short8 a1 = *(const short8*)(A + aoff1);
#pragma unroll
    for (int n = 0; n < 4; ++n) {
      short8 bn = *(const short8*)(B + boff[n]);
      acc[0][n] = __builtin_amdgcn_mfma_f32_16x16x32_bf16(a0, bn, acc[0][n], 0, 0, 0);
      acc[1][n] = __builtin_amdgcn_mfma_f32_16x16x32_bf16(a1, bn, acc[1][n], 0, 0, 0);
    }
    asm volatile("s_waitcnt vmcnt(0)" ::: "memory");
    __syncthreads();
  }

  // epilogue: C/D mapping col=lane&15, row=(lane>>4)*4+reg  [m89-verified]
#pragma unroll
  for (int n = 0; n < 4; ++n) {
    int col = 64 * wn + 16 * n + fr;
    float bias = kbias[col] + cbias[col];
#pragma unroll
    for (int m = 0; m < 2; ++m) {
      int row = mb + 32 * wm + 16 * m + q * 4;
      f32x4 v = acc[m][n];
#pragma unroll
      for (int r = 0; r < 4; ++r)
        out[(size_t)(row + r) * 128 + col] = v[r] + bias;
    }
  }
}

// ---------------------------------------------------------------------------
extern "C" void kernel_launch(void* const* d_in, const int* in_sizes, int n_in,
                              void* d_out, int out_size, void* d_ws, size_t ws_size,
                              hipStream_t stream) {
  const float* x  = (const float*)d_in[0];
  const float* sk = (const float*)d_in[1];   // (288, 8, 128)
  const float* sf = (const float*)d_in[2];   // (288, 128)
  const float* kb = (const float*)d_in[3];   // (128,)
  const float* cb = (const float*)d_in[4];   // (128,)
  float* out = (float*)d_out;                // (32,30,30,128) f32

  char* ws = (char*)d_ws;
  __hip_bfloat16* feat = (__hip_bfloat16*)ws;                 // 18.9 MB
  __hip_bfloat16* wpk  = (__hip_bfloat16*)(ws + FEAT_BYTES);  // 663 KB

  hipLaunchKernelGGL(kan_featurize, dim3(NELEM / 256), dim3(256), 0, stream, x, feat);
  hipLaunchKernelGGL(kan_pack_w, dim3((KCHUNKS * F_OUT * 32) / 256), dim3(256), 0, stream,
                     sk, sf, wpk);
  hipLaunchKernelGGL(kan_gemm, dim3(NPIX / 64), dim3(256), 0, stream,
                     feat, wpk, kb, cb, out);
}

// Round 3
// 112.071 us; speedup vs baseline: 1.0286x; 1.0286x over previous
//
#include <hip/hip_runtime.h>
#include <hip/hip_bf16.h>

// ---------------------------------------------------------------------------
// Conv2DKAN: out[b,ho,wo,f] = sum_{di,dj,c,k} feat(x[b,ho+di,wo+dj,c])_k * W[(di,dj,k,c), f]
// feat_k = cubic B-spline basis (k<8) or silu (k==8); W = sk*sf (k<8) or sf.
// One implicit GEMM: M=28800 pixels, N=128 filters, K=81 chunks * 32 channels.
// R3: 4-stage LDS ring, prefetch depth 3, counted vmcnt(6) + raw s_barrier
//     (T3+T4), bijective XCD swizzle (T1). Was: 2-buf + full drain per iter.
// ---------------------------------------------------------------------------

#define C_IN   32
#define F_OUT  128
#define BATCH  32
#define HIN    32
#define WIN    32
#define HO_    30
#define WO_    30
#define NPIX   (BATCH*HO_*WO_)        // 28800
#define NELEM  (BATCH*HIN*WIN*C_IN)   // 1048576
#define NBASIS 9                      // 8 spline + 1 silu
#define KCHUNKS 81                    // 9 window positions * 9 basis slots
#define FEAT_BYTES  ((size_t)NELEM*NBASIS*2)       // 18,874,368
#define WPACK_BYTES ((size_t)KCHUNKS*F_OUT*32*2)   // 663,552

typedef __attribute__((ext_vector_type(8))) short short8;   // 8 bf16 = 4 VGPR
typedef __attribute__((ext_vector_type(4))) float f32x4;

// async global->LDS, 16B per lane. LDS dest must be linear-in-lane (HW uses
// wave-uniform base + lane*16); our dest = base + tid*16 satisfies this.
#define GLOAD_LDS16(g, l) \
  __builtin_amdgcn_global_load_lds((const __attribute__((address_space(1))) void*)(g), \
                                   (__attribute__((address_space(3))) void*)(l), 16, 0, 0)

// ---------------------------------------------------------------------------
// Kernel A: featurize. feat[bhw][k][c] bf16, 64B per (bhw,k) row.
// Knots g[j] = -2.2 + 0.4j, j=0..11 (GRID_MIN-3h .. GRID_MAX+3h, h=0.4).
// ---------------------------------------------------------------------------
__global__ __launch_bounds__(256) void kan_featurize(
    const float* __restrict__ x, __hip_bfloat16* __restrict__ feat) {
  int idx = blockIdx.x * 256 + threadIdx.x;   // exact grid, no tail
  float v = x[idx];

  float b0[11], b1[10], b2[9], b3[8];
#pragma unroll
  for (int j = 0; j < 11; ++j) {
    float gj  = -2.2f + 0.4f * (float)j;
    float gj1 = -2.2f + 0.4f * (float)(j + 1);
    b0[j] = (v >= gj && v < gj1) ? 1.0f : 0.0f;
  }
#pragma unroll
  for (int j = 0; j < 10; ++j) {  // order 1: denom 0.4
    float gj = -2.2f + 0.4f * (float)j;
    b1[j] = (v - gj) * 2.5f * b0[j] + ((gj + 0.8f) - v) * 2.5f * b0[j + 1];
  }
#pragma unroll
  for (int j = 0; j < 9; ++j) {   // order 2: denom 0.8
    float gj = -2.2f + 0.4f * (float)j;
    b2[j] = (v - gj) * 1.25f * b1[j] + ((gj + 1.2f) - v) * 1.25f * b1[j + 1];
  }
#pragma unroll
  for (int j = 0; j < 8; ++j) {   // order 3: denom 1.2
    float gj = -2.2f + 0.4f * (float)j;
    b3[j] = (v - gj) * (1.0f/1.2f) * b2[j] + ((gj + 1.6f) - v) * (1.0f/1.2f) * b2[j + 1];
  }
  float sil = v / (1.0f + __expf(-v));

  int bhw = idx >> 5, c = idx & 31;
  __hip_bfloat16* o = feat + (size_t)bhw * (NBASIS * 32) + c;
#pragma unroll
  for (int k = 0; k < 8; ++k) o[k * 32] = __float2bfloat16(b3[k]);
  o[8 * 32] = __float2bfloat16(sil);
}

// ---------------------------------------------------------------------------
// Kernel C: pack W -> [kc][col][4 x 16B parts, XOR-swizzled][8 bf16].
// kc = dd*9 + k, dd = di*3+dj; i = dd*32 + csub.
// Swizzle: part p of col r stored at slot p ^ ((r>>1)&3)  (self-inverse).
// ---------------------------------------------------------------------------
__global__ __launch_bounds__(256) void kan_pack_w(
    const float* __restrict__ sk, const float* __restrict__ sf,
    __hip_bfloat16* __restrict__ wp) {
  int tid = blockIdx.x * 256 + threadIdx.x;   // 331776 total, exact
  int csub = tid & 31;
  int col  = (tid >> 5) & 127;
  int kc   = tid >> 12;
  int dd = kc / 9, k = kc - dd * 9;
  int i = dd * 32 + csub;
  float w = sf[i * 128 + col];
  if (k < 8) w *= sk[(i * 8 + k) * 128 + col];
  int part = csub >> 3, within = csub & 7;
  int slot = part ^ ((col >> 1) & 3);
  wp[(size_t)kc * 4096 + col * 32 + slot * 8 + within] = __float2bfloat16(w);
}

// ---------------------------------------------------------------------------
// Kernel B: implicit GEMM. 450 blocks x 256 thr (4 waves, 2x2 of 32x64).
// LDS ring: A 4x4KB at [0,16K), B 4x8KB at [16K,48K). Prefetch depth 3.
// Steady-state wait: vmcnt(6) -> stage k+1 landed, stages k+2,k+3 in flight.
// ---------------------------------------------------------------------------
__global__ __launch_bounds__(256) void kan_gemm(
    const __hip_bfloat16* __restrict__ featb, const __hip_bfloat16* __restrict__ wpb,
    const float* __restrict__ kbias, const float* __restrict__ cbias,
    float* __restrict__ out) {
  __shared__ char lds[49152];
  const char* feat = (const char*)featb;
  const char* wp   = (const char*)wpb;

  int tid  = threadIdx.x;
  int lane = tid & 63, wid = tid >> 6;
  int wm = wid >> 1, wn = wid & 1;
  int q = lane >> 4, fr = lane & 15;

  // bijective XCD swizzle (m204): nwg=450=8*56+2 -> xcd 0,1 get 57 blocks.
  int orig = blockIdx.x;
  int xcd = orig & 7, sub = orig >> 3;
  int swz = (xcd < 2 ? xcd * 57 : 114 + (xcd - 2) * 56) + sub;
  int mb = swz * 64;

  // --- A staging source: thread t -> (row=t>>2, slot=t&3); fetch part p s.t.
  //     stored slot holds part p = slot ^ ((row>>1)&3).
  int arow = tid >> 2, aslot = tid & 3;
  int apix = mb + arow;
  int wo = apix % 30, t30 = apix / 30;
  int ho = t30 % 30,  bb  = t30 / 30;
  const char* asrc = feat + (size_t)((bb * 32 + ho) * 32 + wo) * 576
                          + (size_t)((aslot ^ ((arow >> 1) & 3)) * 16);

  // --- fragment LDS byte offsets (swizzled reads)
  int ar0 = 32 * wm + fr, ar1 = ar0 + 16;
  int aoff0 = ar0 * 64 + ((q ^ ((ar0 >> 1) & 3)) * 16);
  int aoff1 = ar1 * 64 + ((q ^ ((ar1 >> 1) & 3)) * 16);
  int boff[4];
#pragma unroll
  for (int n = 0; n < 4; ++n) {
    int col = 64 * wn + 16 * n + fr;
    boff[n] = col * 64 + ((q ^ ((col >> 1) & 3)) * 16);
  }

  f32x4 acc[2][4];
#pragma unroll
  for (int m = 0; m < 2; ++m)
#pragma unroll
    for (int n = 0; n < 4; ++n) acc[m][n] = (f32x4)(0.0f);

  auto stage = [&](int kc) {
    int s = kc & 3;
    int dd = kc / 9, k = kc - dd * 9;          // uniform scalar math
    int di = dd / 3, dj = dd - di * 3;
    int au = (di * 32 + dj) * 576 + k * 64;    // window shift + basis slot
    GLOAD_LDS16(asrc + au, lds + s * 4096 + tid * 16);
    const char* wsrc = wp + (size_t)kc * 8192 + tid * 16;
    GLOAD_LDS16(wsrc,        lds + 16384 + s * 8192 + tid * 16);
    GLOAD_LDS16(wsrc + 4096, lds + 16384 + s * 8192 + 4096 + tid * 16);
  };

  auto compute = [&](int s) {
    const char* A = lds + s * 4096;
    const char* B = lds + 16384 + s * 8192;
    short8 a0 = *(const short8*)(A + aoff0);
    short8 a1 = *(const short8*)(A + aoff1);
#pragma unroll
    for (int n = 0; n < 4; ++n) {
      short8 bn = *(const short8*)(B + boff[n]);
      acc[0][n] = __builtin_amdgcn_mfma_f32_16x16x32_bf16(a0, bn, acc[0][n], 0, 0, 0);
      acc[1][n] = __builtin_amdgcn_mfma_f32_16x16x32_bf16(a1, bn, acc[1][n], 0, 0, 0);
    }
  };

  // prologue: fill 3 stages, wait for stage 0 (6 younger loads may fly)
  stage(0); stage(1); stage(2);
  asm volatile("s_waitcnt vmcnt(6)" ::: "memory");
  __builtin_amdgcn_s_barrier();
  __builtin_amdgcn_sched_barrier(0);

  // main loop: k=0..77. End-of-iter wait vmcnt(6): stage k+1 complete,
  // stages k+2,k+3 (6 loads) stay in flight across the barrier.
  for (int kc = 0; kc < KCHUNKS - 3; ++kc) {
    stage(kc + 3);               // overwrites buf[(kc-1)&3], consumed last iter
    compute(kc & 3);
    asm volatile("s_waitcnt vmcnt(6) lgkmcnt(0)" ::: "memory");
    __builtin_amdgcn_s_barrier();
    __builtin_amdgcn_sched_barrier(0);
  }
  // drain: stages 78,79,80 all issued; finish them, then barrier-free tail.
  asm volatile("s_waitcnt vmcnt(0)" ::: "memory");
  __builtin_amdgcn_s_barrier();
  __builtin_amdgcn_sched_barrier(0);
  compute((KCHUNKS - 3) & 3);
  compute((KCHUNKS - 2) & 3);
  compute((KCHUNKS - 1) & 3);

  // epilogue: C/D mapping col=lane&15, row=(lane>>4)*4+reg  [m89-verified]
#pragma unroll
  for (int n = 0; n < 4; ++n) {
    int col = 64 * wn + 16 * n + fr;
    float bias = kbias[col] + cbias[col];
#pragma unroll
    for (int m = 0; m < 2; ++m) {
      int row = mb + 32 * wm + 16 * m + q * 4;
      f32x4 v = acc[m][n];
#pragma unroll
      for (int r = 0; r < 4; ++r)
        out[(size_t)(row + r) * 128 + col] = v[r] + bias;
    }
  }
}

// ---------------------------------------------------------------------------
extern "C" void kernel_launch(void* const* d_in, const int* in_sizes, int n_in,
                              void* d_out, int out_size, void* d_ws, size_t ws_size,
                              hipStream_t stream) {
  const float* x  = (const float*)d_in[0];
  const float* sk = (const float*)d_in[1];   // (288, 8, 128)
  const float* sf = (const float*)d_in[2];   // (288, 128)
  const float* kb = (const float*)d_in[3];   // (128,)
  const float* cb = (const float*)d_in[4];   // (128,)
  float* out = (float*)d_out;                // (32,30,30,128) f32

  char* ws = (char*)d_ws;
  __hip_bfloat16* feat = (__hip_bfloat16*)ws;                 // 18.9 MB
  __hip_bfloat16* wpk  = (__hip_bfloat16*)(ws + FEAT_BYTES);  // 663 KB

  hipLaunchKernelGGL(kan_featurize, dim3(NELEM / 256), dim3(256), 0, stream, x, feat);
  hipLaunchKernelGGL(kan_pack_w, dim3((KCHUNKS * F_OUT * 32) / 256), dim3(256), 0, stream,
                     sk, sf, wpk);
  hipLaunchKernelGGL(kan_gemm, dim3(NPIX / 64), dim3(256), 0, stream,
                     feat, wpk, kb, cb, out);
}